// Round 4
// baseline (436.177 us; speedup 1.0000x reference)
//
#include <hip/hip_runtime.h>
#include <hip/hip_bf16.h>

#define B_ROWS 256
#define S_SUP  65536
#define D_DIM  768
#define QSZ    512
#define NCHUNK 12          // 768 / 64
#define ACH_BYTES 32768    // A chunk: 256 rows * 64 k * 2 B (bf16)
#define BCH_BYTES 8192     // B chunk:  64 rows * 64 k * 2 B (bf16)

typedef short bf16x8 __attribute__((ext_vector_type(8)));
typedef float f32x4  __attribute__((ext_vector_type(4)));

__device__ __forceinline__ bf16x8 cvt8(float4 a, float4 b) {
  bf16x8 r;
  r[0] = (short)(__float_as_uint(a.x) >> 16);
  r[1] = (short)(__float_as_uint(a.y) >> 16);
  r[2] = (short)(__float_as_uint(a.z) >> 16);
  r[3] = (short)(__float_as_uint(a.w) >> 16);
  r[4] = (short)(__float_as_uint(b.x) >> 16);
  r[5] = (short)(__float_as_uint(b.y) >> 16);
  r[6] = (short)(__float_as_uint(b.z) >> 16);
  r[7] = (short)(__float_as_uint(b.w) >> 16);
  return r;
}

__device__ __forceinline__ void gl_lds16(const void* g, void* l) {
  __builtin_amdgcn_global_load_lds(
      (const __attribute__((address_space(1))) unsigned int*)g,
      (__attribute__((address_space(3))) unsigned int*)l, 16, 0, 0);
}

// block-wide sum (float), result broadcast to all 256 threads (4 waves)
__device__ __forceinline__ float block_sum(float v) {
  __shared__ float tmp[4];
  #pragma unroll
  for (int m = 32; m >= 1; m >>= 1) v += __shfl_xor(v, m, 64);
  __syncthreads();
  if ((threadIdx.x & 63) == 0) tmp[threadIdx.x >> 6] = v;
  __syncthreads();
  return tmp[0] + tmp[1] + tmp[2] + tmp[3];
}

__device__ __forceinline__ double block_sum_d(double v) {
  __shared__ double tmp[4];
  #pragma unroll
  for (int m = 32; m >= 1; m >>= 1) v += __shfl_xor(v, m, 64);
  __syncthreads();
  if ((threadIdx.x & 63) == 0) tmp[threadIdx.x >> 6] = v;
  __syncthreads();
  return tmp[0] + tmp[1] + tmp[2] + tmp[3];
}

// ---- kernel 1: augs[j-1] = normalize(V[j]*L); j==0 -> org_bf16 (swizzled chunk image)
//      block 0 also zeroes gmax/bden (init fused).
// org_bf16 layout: chunk c (k in [64c,64c+64)) is a 32 KB image: row r = 128 B,
// 8 groups of 16 B; group jg stored at slot (jg ^ (r&7)).
__global__ __launch_bounds__(256) void prep_kernel(const float* __restrict__ V,
                                                   const float* __restrict__ L,
                                                   unsigned short* __restrict__ orgb,
                                                   float* __restrict__ augs,
                                                   unsigned long long* __restrict__ gmax,
                                                   double* __restrict__ bden) {
  int jb = blockIdx.x;            // 0..1023
  int j = jb >> 8, b = jb & 255;
  int tid = threadIdx.x;
  if (jb == 0) {                  // fused init
    gmax[tid] = 0ull;
    for (int i = tid; i < 3 * B_ROWS; i += 256) bden[i] = 0.0;
  }
  const float* v = V + ((size_t)j * B_ROWS + b) * D_DIM;
  const float* l = L + (size_t)b * D_DIM;
  float p[3]; float ssq = 0.f;
  #pragma unroll
  for (int i = 0; i < 3; ++i) {
    int k = tid + 256 * i;
    p[i] = v[k] * l[k];
    ssq += p[i] * p[i];
  }
  ssq = block_sum(ssq);
  float inv = 1.0f / fmaxf(sqrtf(ssq), 1e-12f);
  if (j == 0) {
    #pragma unroll
    for (int i = 0; i < 3; ++i) {
      int k = tid + 256 * i;
      unsigned short hv = (unsigned short)(__float_as_uint(p[i] * inv) >> 16);
      int c = k >> 6, kk = k & 63, jg = kk >> 3, e = kk & 7;
      orgb[c * 16384 + b * 64 + ((jg ^ (b & 7)) << 3) + e] = hv;
    }
  } else {
    float* dst = augs + ((size_t)(j - 1) * B_ROWS + b) * D_DIM;
    #pragma unroll
    for (int i = 0; i < 3; ++i) dst[tid + 256 * i] = p[i] * inv;
  }
}

// ---- kernel 2: sim = org @ sf^T, software-pipelined dbuf, M-split waves ----
// wave w owns m in [64w, 64w+64); block owns n in [64*bx, 64*bx+64).
__global__ __launch_bounds__(256, 2) void sim_argmax_kernel(const unsigned short* __restrict__ orgb,
                                                            const float* __restrict__ sf,
                                                            unsigned long long* __restrict__ gmax) {
  const int tid  = threadIdx.x;
  const int w    = tid >> 6;
  const int lid  = tid & 63;
  const int quad = lid >> 4;
  const int r15  = lid & 15;
  const int s0   = blockIdx.x * 64;

  __shared__ __align__(16) char bufA[2][ACH_BYTES];
  __shared__ __align__(16) char bufB[2][BCH_BYTES];

  f32x4 acc[4][4];
  #pragma unroll
  for (int mt = 0; mt < 4; ++mt)
    #pragma unroll
    for (int nt = 0; nt < 4; ++nt) acc[mt][nt] = (f32x4){0.f, 0.f, 0.f, 0.f};

  // B staging assignment: thread (w,lid) covers sf row (s0+lid), k-seg [w*16, w*16+16)
  const float* bsrc = sf + (size_t)(s0 + lid) * D_DIM + w * 16;
  const char*  asrc = (const char*)orgb;
  const int lrow = lid * 128;
  const int sl0  = (((2 * w)     ^ (lid & 7)) << 4);
  const int sl1  = (((2 * w + 1) ^ (lid & 7)) << 4);

  // prologue: stage chunk 0 (A via global_load_lds, B via regs+cvt+ds_write)
  {
    const char* g = asrc + w * 8192 + lid * 16;
    char* l = bufA[0] + w * 8192;
    #pragma unroll
    for (int i = 0; i < 8; ++i) gl_lds16(g + i * 1024, l + i * 1024);
    const float4* bp = (const float4*)bsrc;
    float4 q0 = bp[0], q1 = bp[1], q2 = bp[2], q3 = bp[3];
    *(bf16x8*)(bufB[0] + lrow + sl0) = cvt8(q0, q1);
    *(bf16x8*)(bufB[0] + lrow + sl1) = cvt8(q2, q3);
  }
  __syncthreads();

  for (int c = 0; c < NCHUNK; ++c) {
    float4 q0, q1, q2, q3;
    const int nb = (c + 1) & 1;
    if (c < NCHUNK - 1) {
      // issue next A-chunk DMA + next B loads BEFORE consuming current chunk
      const char* g = asrc + (c + 1) * ACH_BYTES + w * 8192 + lid * 16;
      char* l = bufA[nb] + w * 8192;
      #pragma unroll
      for (int i = 0; i < 8; ++i) gl_lds16(g + i * 1024, l + i * 1024);
      const float4* bp = (const float4*)(bsrc + (c + 1) * 64);
      q0 = bp[0]; q1 = bp[1]; q2 = bp[2]; q3 = bp[3];
    }
    const char* Ac = bufA[c & 1];
    const char* Bc = bufB[c & 1];
    #pragma unroll
    for (int k1 = 0; k1 < 2; ++k1) {
      const int slot = (((k1 * 4 + quad) ^ (r15 & 7)) << 4);
      bf16x8 af[4], bfr[4];
      #pragma unroll
      for (int mt = 0; mt < 4; ++mt)
        af[mt] = *(const bf16x8*)(Ac + (64 * w + 16 * mt + r15) * 128 + slot);
      #pragma unroll
      for (int nt = 0; nt < 4; ++nt)
        bfr[nt] = *(const bf16x8*)(Bc + (16 * nt + r15) * 128 + slot);
      #pragma unroll
      for (int mt = 0; mt < 4; ++mt)
        #pragma unroll
        for (int nt = 0; nt < 4; ++nt)
          acc[mt][nt] = __builtin_amdgcn_mfma_f32_16x16x32_bf16(af[mt], bfr[nt], acc[mt][nt], 0, 0, 0);
    }
    if (c < NCHUNK - 1) {
      *(bf16x8*)(bufB[nb] + lrow + sl0) = cvt8(q0, q1);
      *(bf16x8*)(bufB[nb] + lrow + sl1) = cvt8(q2, q3);
      __syncthreads();
    }
  }

  // epilogue: argmax over n, fully wave-local.
  // C/D: col = r15 (n), row = quad*4 + reg (m within tile)
  #pragma unroll
  for (int mt = 0; mt < 4; ++mt) {
    #pragma unroll
    for (int r = 0; r < 4; ++r) {
      float v = acc[mt][0][r];
      int idx = s0 + r15;
      #pragma unroll
      for (int nt = 1; nt < 4; ++nt) {
        float c2 = acc[mt][nt][r];
        if (c2 > v) { v = c2; idx = s0 + nt * 16 + r15; }  // strict >: keeps first
      }
      #pragma unroll
      for (int m = 1; m < 16; m <<= 1) {
        float ov = __shfl_xor(v, m, 64);
        int   oi = __shfl_xor(idx, m, 64);
        if (ov > v || (ov == v && oi < idx)) { v = ov; idx = oi; }
      }
      if (r15 == 0) {
        int mg = 64 * w + 16 * mt + 4 * quad + r;
        unsigned u = __float_as_uint(v);
        unsigned key = (u & 0x80000000u) ? ~u : (u | 0x80000000u);
        unsigned long long packed = ((unsigned long long)key << 32) |
                                    (unsigned long long)(0xFFFFFFFFu - (unsigned)idx);
        atomicMax(gmax + mg, packed);
      }
    }
  }
}

// ---- kernel 3: fused nn (normalize + nnT + num) and GPS queue denominator ----
__global__ __launch_bounds__(256) void nnqueue_kernel(const unsigned long long* __restrict__ gmax,
                                                      const float* __restrict__ sf,
                                                      const float* __restrict__ augs,
                                                      const float* __restrict__ gps,
                                                      const float* __restrict__ sgps,
                                                      float* __restrict__ nnT,
                                                      float* __restrict__ num,
                                                      double* __restrict__ qden) {
  int b = blockIdx.x, tid = threadIdx.x;
  int w = tid >> 6, lane = tid & 63;
  __shared__ __align__(16) float s_nn[D_DIM];
  __shared__ int qidx[QSZ];
  __shared__ int s_count;
  __shared__ int s_wcnt[4];
  __shared__ double s_gsum[16];

  int idx = (int)(0xFFFFFFFFu - (unsigned)(gmax[b] & 0xFFFFFFFFull));
  const float* row = sf + (size_t)idx * D_DIM;
  float p[3]; float ssq = 0.f;
  #pragma unroll
  for (int i = 0; i < 3; ++i) { p[i] = row[tid + 256 * i]; ssq += p[i] * p[i]; }
  ssq = block_sum(ssq);
  float inv = 1.0f / fmaxf(sqrtf(ssq), 1e-12f);
  const float* a0 = augs + (size_t)b * D_DIM;    // augs[0][b]
  float dot = 0.f;
  #pragma unroll
  for (int i = 0; i < 3; ++i) {
    int k = tid + 256 * i;
    float nv = p[i] * inv;
    s_nn[k] = nv;
    nnT[(size_t)k * B_ROWS + b] = nv;
    dot += nv * a0[k];
  }
  dot = block_sum(dot);                           // barriers inside make s_nn visible
  if (tid == 0) { num[b] = dot * 10.0f; s_count = 0; }
  __syncthreads();

  const float r = 0.017453292519943295f;
  float lat1 = gps[b * 2 + 0] * r, lon1 = gps[b * 2 + 1] * r;
  float cl1 = cosf(lat1);
  int base = 0;
  while (true) {
    int count = s_count;
    if (count >= QSZ || base >= S_SUP) break;
    int s = base + tid;
    float lat2 = sgps[s * 2 + 0] * r, lon2 = sgps[s * 2 + 1] * r;
    float sdlat = sinf((lat2 - lat1) * 0.5f);
    float sdlon = sinf((lon2 - lon1) * 0.5f);
    float a = sdlat * sdlat + cl1 * cosf(lat2) * sdlon * sdlon;
    a = fminf(fmaxf(a, 0.f), 1.f);
    float d = 2.0f * 6371.0088f * asinf(sqrtf(a));
    bool valid = d > 25.0f;

    unsigned long long m = __ballot(valid);
    int wc = __popcll(m);
    if (lane == 0) s_wcnt[w] = wc;
    __syncthreads();
    int wbase = count;
    for (int i = 0; i < w; ++i) wbase += s_wcnt[i];
    int pos = wbase + __popcll(m & ((1ull << lane) - 1ull));
    if (valid && pos < QSZ) qidx[pos] = s;
    __syncthreads();
    if (tid == 0) {
      int total = s_wcnt[0] + s_wcnt[1] + s_wcnt[2] + s_wcnt[3];
      s_count = min(QSZ, count + total);
    }
    base += 256;
    __syncthreads();
  }
  int count = s_count;

  // 16 lanes per row, 16 rows in flight per block
  int g  = lane >> 4;
  int l2 = lane & 15;
  double acc = 0.0;
  const float4* nn4 = (const float4*)s_nn;
  for (int q = w * 4 + g; q < count; q += 16) {
    const float4* rr = (const float4*)(sf + (size_t)qidx[q] * D_DIM);
    float d2 = 0.f;
    #pragma unroll
    for (int i = 0; i < 12; ++i) {
      float4 a = rr[l2 + 16 * i];
      float4 nv = nn4[l2 + 16 * i];
      d2 += a.x * nv.x + a.y * nv.y + a.z * nv.z + a.w * nv.w;
    }
    #pragma unroll
    for (int m2 = 8; m2 >= 1; m2 >>= 1) d2 += __shfl_xor(d2, m2, 16);
    if (l2 == 0) acc += exp((double)d2 * 10.0);   // double: self-hit dot ~27.7
  }
  if (l2 == 0) s_gsum[w * 4 + g] = acc;
  __syncthreads();
  if (tid == 0) {
    double t = (double)(QSZ - count);
    #pragma unroll
    for (int i = 0; i < 16; ++i) t += s_gsum[i];
    qden[b] = t;
  }
}

// ---- kernel 4: batch_den[j][b] += sum_i exp(10*dot(nn_b, aug_ji)) (double acc) ----
__global__ __launch_bounds__(256) void bden_kernel(const float* __restrict__ augs,
                                                   const float* __restrict__ nnT,
                                                   double* __restrict__ bden) {
  int jc = blockIdx.x;                 // 0..191
  int j = jc >> 6, c = jc & 63;
  int i0 = c * 4;
  __shared__ float s_aug[4 * D_DIM];
  const float* src = augs + ((size_t)j * B_ROWS + i0) * D_DIM;
  for (int idx = threadIdx.x; idx < 4 * D_DIM; idx += 256) s_aug[idx] = src[idx];
  __syncthreads();
  int b = threadIdx.x;
  float a0 = 0.f, a1 = 0.f, a2 = 0.f, a3 = 0.f;
  for (int k = 0; k < D_DIM; ++k) {
    float nv = nnT[(size_t)k * B_ROWS + b];
    a0 += nv * s_aug[k];
    a1 += nv * s_aug[D_DIM + k];
    a2 += nv * s_aug[2 * D_DIM + k];
    a3 += nv * s_aug[3 * D_DIM + k];
  }
  double v = exp((double)a0 * 10.0) + exp((double)a1 * 10.0) +
             exp((double)a2 * 10.0) + exp((double)a3 * 10.0);
  atomicAdd(&bden[j * B_ROWS + b], v);
}

// ---- kernel 5: final scalar loss (double) ----
__global__ __launch_bounds__(256) void loss_kernel(const float* __restrict__ num,
                                                   const double* __restrict__ bden,
                                                   const double* __restrict__ qden,
                                                   float* __restrict__ out) {
  int b = threadIdx.x;
  double q = qden[b];
  double n = (double)num[b];
  double t = 0.0;
  #pragma unroll
  for (int j = 0; j < 3; ++j) t += n - log(bden[j * B_ROWS + b] + q);
  t = block_sum_d(t);
  if (b == 0) out[0] = (float)(-t / 256.0);
}

extern "C" void kernel_launch(void* const* d_in, const int* in_sizes, int n_in,
                              void* d_out, int out_size, void* d_ws, size_t ws_size,
                              hipStream_t stream) {
  const float* V    = (const float*)d_in[0];   // (4,256,768)
  const float* L    = (const float*)d_in[1];   // (256,768)
  const float* gps  = (const float*)d_in[2];   // (256,2)
  const float* sf   = (const float*)d_in[3];   // (65536,768)
  const float* sgps = (const float*)d_in[4];   // (65536,2)
  float* out = (float*)d_out;

  char* ws = (char*)d_ws;
  size_t off = 0;
  unsigned short* orgb = (unsigned short*)(ws + off); off += 393216;  // 12 chunks * 32 KB
  float* augs = (float*)(ws + off); off += 2359296;                   // 3*256*768*4
  float* nnT  = (float*)(ws + off); off += 786432;                    // 768*256*4
  float* num  = (float*)(ws + off); off += 1024;
  double* bden = (double*)(ws + off); off += 6144;
  double* qden = (double*)(ws + off); off += 2048;
  unsigned long long* gmax = (unsigned long long*)(ws + off); off += 2048;

  prep_kernel<<<1024, 256, 0, stream>>>(V, L, orgb, augs, gmax, bden);
  sim_argmax_kernel<<<S_SUP / 64, 256, 0, stream>>>(orgb, sf, gmax);
  nnqueue_kernel<<<B_ROWS, 256, 0, stream>>>(gmax, sf, augs, gps, sgps, nnT, num, qden);
  bden_kernel<<<192, 256, 0, stream>>>(augs, nnT, bden);
  loss_kernel<<<1, 256, 0, stream>>>(num, bden, qden, out);
}